// Round 6
// baseline (70.249 us; speedup 1.0000x reference)
//
#include <hip/hip_runtime.h>
#include <math.h>

#define NN 4096
#define FF 128
#define DD 64
#define HH 4
#define NC 256  // HH*DD output columns

typedef _Float16 f16x8 __attribute__((ext_vector_type(8)));
typedef _Float16 f16x2 __attribute__((ext_vector_type(2)));
typedef float    f32x4 __attribute__((ext_vector_type(4)));

// ---------------------------------------------------------------------------
// Kernel 0: adjacency int32 -> bitmask. adjw[n*128 + w] bit b = (adj[n][w*32+b])
// ---------------------------------------------------------------------------
__global__ __launch_bounds__(256) void adjbits_kernel(
    const int* __restrict__ adj, unsigned int* __restrict__ adjw)
{
    const int row  = blockIdx.x;
    const int wv   = threadIdx.x >> 6;
    const int lane = threadIdx.x & 63;
    for (int c = wv; c < 64; c += 4) {
        int a = adj[(size_t)row * NN + c * 64 + lane];
        unsigned long long m = __ballot(a != 0);
        if (lane == 0) {
            adjw[row * 128 + c * 2]     = (unsigned int)m;
            adjw[row * 128 + c * 2 + 1] = (unsigned int)(m >> 32);
        }
    }
}

// ---------------------------------------------------------------------------
// Kernel 1: h = features @ W[h]; emit Bpack (f16 MFMA-B-fragment-ordered
// tiles: Bpack[h][chunk][cb][lane][8], 4KB contiguous per 64d x 32m chunk)
// and f16 exp tables Es, Fs, En, Fn ([h][n]).
// Block = (32 nodes, 1 head) = exactly one Bpack chunk.
// ---------------------------------------------------------------------------
__global__ __launch_bounds__(256) void prep_kernel(
    const float* __restrict__ feats, const float* __restrict__ W,
    const float* __restrict__ ak, _Float16* __restrict__ Bpack,
    _Float16* __restrict__ Es, _Float16* __restrict__ Fs,
    _Float16* __restrict__ En, _Float16* __restrict__ Fn)
{
    __shared__ float Wt[64 * 132];
    __shared__ float ft[32 * 128];
    __shared__ float hlds[32 * 65];
    const int t  = threadIdx.x;
    const int h  = blockIdx.y;
    const int n0 = blockIdx.x * 32;

    {
        const float* Wh = W + h * (FF * DD);
        #pragma unroll
        for (int j = 0; j < 8; ++j) {
            int idx = j * 256 + t;
            int f   = idx >> 4;
            int d4  = idx & 15;
            float4 v = ((const float4*)Wh)[idx];
            Wt[(d4 * 4 + 0) * 132 + f] = v.x;
            Wt[(d4 * 4 + 1) * 132 + f] = v.y;
            Wt[(d4 * 4 + 2) * 132 + f] = v.z;
            Wt[(d4 * 4 + 3) * 132 + f] = v.w;
        }
        #pragma unroll
        for (int j = 0; j < 4; ++j) {
            int idx = j * 256 + t;
            int r = idx >> 5, f4 = idx & 31;
            ((float4*)ft)[r * 32 + f4] = ((const float4*)feats)[(size_t)(n0 + r) * 32 + f4];
        }
    }
    __syncthreads();

    const int d   = t & 63;
    const int wid = t >> 6;
    float acc[8];
    #pragma unroll
    for (int j = 0; j < 8; ++j) acc[j] = 0.f;

    for (int f4 = 0; f4 < 32; ++f4) {
        const float4 w4 = *(const float4*)&Wt[d * 132 + f4 * 4];
        #pragma unroll
        for (int j = 0; j < 8; ++j) {
            const int r = wid + 4 * j;
            const float4 fv = *(const float4*)&ft[r * 128 + f4 * 4];
            acc[j] += fv.x * w4.x + fv.y * w4.y + fv.z * w4.z + fv.w * w4.w;
        }
    }

    const float aks = ak[h * 128 + d];
    const float akn = ak[h * 128 + 64 + d];
    #pragma unroll
    for (int j = 0; j < 8; ++j) {
        const int r = wid + 4 * j;
        const float hv = acc[j];
        hlds[r * 65 + d] = hv;
        float v1 = hv * aks;
        float v2 = hv * akn;
        #pragma unroll
        for (int m = 32; m >= 1; m >>= 1) {
            v1 += __shfl_xor(v1, m, 64);
            v2 += __shfl_xor(v2, m, 64);
        }
        if (d == 0) {
            Es[h * NN + n0 + r] = (_Float16)__expf(v1);
            Fs[h * NN + n0 + r] = (_Float16)__expf(0.2f * v1);
            En[h * NN + n0 + r] = (_Float16)__expf(v2);
            Fn[h * NN + n0 + r] = (_Float16)__expf(0.2f * v2);
        }
    }
    __syncthreads();

    // Bpack write: thread t = (cb = t>>6, lane l = t&63); element j is
    // Ht[cb*16 + (l&15)][m0 + (l>>4)*8 + j]  ==  hlds[(l>>4)*8+j][cb*16+(l&15)]
    const int cb = t >> 6;
    const int l  = t & 63;
    const int lr = l & 15;
    const int kg = l >> 4;
    f16x8 v;
    #pragma unroll
    for (int j = 0; j < 8; ++j)
        v[j] = (_Float16)hlds[(kg * 8 + j) * 65 + cb * 16 + lr];
    *(f16x8*)(Bpack + ((size_t)(h * 128 + blockIdx.x)) * 2048 + (cb * 64 + l) * 8) = v;
}

// ---------------------------------------------------------------------------
// Kernel 2: MFMA attention, barrier-free, LDS-free. 1 wave/block;
// grid (128 row-tiles, 4 heads, nsplit). B-frags are lane-contiguous dense
// loads from Bpack (L2-resident), ping-pong prefetched one chunk ahead
// (named regs B_0/B_1; even chunks in B_0, odd in B_1).
// A = mask ? max(Es*En, Fs*Fn) : 0, packed-f16 ALU.
// mfma_f32_16x16x32_f16; C layout col=lane&15, row=(lane>>4)*4+reg.
// ---------------------------------------------------------------------------
__global__ __launch_bounds__(64, 4) void attn_kernel(
    const unsigned int* __restrict__ adjw, const _Float16* __restrict__ Bpack,
    const _Float16* __restrict__ Es, const _Float16* __restrict__ Fs,
    const _Float16* __restrict__ En, const _Float16* __restrict__ Fn,
    float* __restrict__ pacc, float* __restrict__ pden, int ksplit)
{
    const int l  = threadIdx.x;
    const int lr = l & 15;
    const int kg = l >> 4;
    const int h  = blockIdx.y;
    const int n0 = blockIdx.x * 32;
    const int s  = blockIdx.z;

    const int mstart = s * ksplit;
    const int nchunk = ksplit >> 5;
    const int wb     = mstart >> 5;        // mask word base

    const _Float16 es0 = Es[h * NN + n0 + lr],      fs0 = Fs[h * NN + n0 + lr];
    const _Float16 es1 = Es[h * NN + n0 + 16 + lr], fs1 = Fs[h * NN + n0 + 16 + lr];
    const f16x2 es20 = {es0, es0}, fs20 = {fs0, fs0};
    const f16x2 es21 = {es1, es1}, fs21 = {fs1, fs1};

    const _Float16* __restrict__ EnB = En + (size_t)h * NN;
    const _Float16* __restrict__ FnB = Fn + (size_t)h * NN;
    const int row0 = n0 + lr, row1 = n0 + 16 + lr;

    // per-lane Bpack base for this head+split (chunk stride = 2048 f16)
    const _Float16* __restrict__ bp =
        Bpack + ((size_t)(h * 128) + (mstart >> 5)) * 2048 + l * 8;

    f32x4 acc[2][4] = {};
    f32x4 dacc[2]   = {};
    f16x8 ones;
    #pragma unroll
    for (int j = 0; j < 8; ++j) ones[j] = (_Float16)1.0f;

    union U8 { f16x8 v; unsigned int u[4]; };

    f16x8 B_0[4], B_1[4];

#define LOADB(DST, CIDX) do {                                                 \
        int _c = (CIDX); _c = _c < nchunk ? _c : nchunk - 1;                  \
        const _Float16* _b = bp + (size_t)_c * 2048;                          \
        _Pragma("unroll")                                                     \
        for (int _cb = 0; _cb < 4; ++_cb)                                     \
            DST[_cb] = *(const f16x8*)(_b + _cb * 512);                       \
    } while (0)

#define STEP(BREG, C, MW0, MW1) do {                                          \
        const int _m0 = mstart + (C) * 32;                                    \
        const uint4 enq = *(const uint4*)(EnB + _m0 + kg * 8);                \
        const uint4 fnq = *(const uint4*)(FnB + _m0 + kg * 8);                \
        const unsigned int b0 = (MW0) >> (kg * 8);                            \
        const unsigned int b1 = (MW1) >> (kg * 8);                            \
        U8 A0, A1;                                                            \
        _Pragma("unroll")                                                     \
        for (int p = 0; p < 4; ++p) {                                         \
            const unsigned int eu = p == 0 ? enq.x : p == 1 ? enq.y : p == 2 ? enq.z : enq.w; \
            const unsigned int fu = p == 0 ? fnq.x : p == 1 ? fnq.y : p == 2 ? fnq.z : fnq.w; \
            const f16x2 en2 = __builtin_bit_cast(f16x2, eu);                  \
            const f16x2 fn2 = __builtin_bit_cast(f16x2, fu);                  \
            const f16x2 v0 = __builtin_elementwise_max(es20 * en2, fs20 * fn2); \
            const f16x2 v1 = __builtin_elementwise_max(es21 * en2, fs21 * fn2); \
            const unsigned int mm0 = (((b0 >> (2 * p)) & 1u) ? 0x0000FFFFu : 0u) \
                                   | (((b0 >> (2 * p + 1)) & 1u) ? 0xFFFF0000u : 0u); \
            const unsigned int mm1 = (((b1 >> (2 * p)) & 1u) ? 0x0000FFFFu : 0u) \
                                   | (((b1 >> (2 * p + 1)) & 1u) ? 0xFFFF0000u : 0u); \
            A0.u[p] = __builtin_bit_cast(unsigned int, v0) & mm0;             \
            A1.u[p] = __builtin_bit_cast(unsigned int, v1) & mm1;             \
        }                                                                     \
        __builtin_amdgcn_s_setprio(1);                                        \
        _Pragma("unroll")                                                     \
        for (int _cb = 0; _cb < 4; ++_cb) {                                   \
            acc[0][_cb] = __builtin_amdgcn_mfma_f32_16x16x32_f16(A0.v, BREG[_cb], acc[0][_cb], 0, 0, 0); \
            acc[1][_cb] = __builtin_amdgcn_mfma_f32_16x16x32_f16(A1.v, BREG[_cb], acc[1][_cb], 0, 0, 0); \
        }                                                                     \
        dacc[0] = __builtin_amdgcn_mfma_f32_16x16x32_f16(A0.v, ones, dacc[0], 0, 0, 0); \
        dacc[1] = __builtin_amdgcn_mfma_f32_16x16x32_f16(A1.v, ones, dacc[1], 0, 0, 0); \
        __builtin_amdgcn_s_setprio(0);                                        \
    } while (0)

    LOADB(B_0, 0);

    for (int cq = 0; cq < (nchunk >> 2); ++cq) {
        const int c0 = cq * 4;
        const uint4 mk0 = *(const uint4*)&adjw[(size_t)row0 * 128 + wb + c0];
        const uint4 mk1 = *(const uint4*)&adjw[(size_t)row1 * 128 + wb + c0];

        LOADB(B_1, c0 + 1);
        STEP(B_0, c0 + 0, mk0.x, mk1.x);
        LOADB(B_0, c0 + 2);
        STEP(B_1, c0 + 1, mk0.y, mk1.y);
        LOADB(B_1, c0 + 3);
        STEP(B_0, c0 + 2, mk0.z, mk1.z);
        LOADB(B_0, c0 + 4);
        STEP(B_1, c0 + 3, mk0.w, mk1.w);
    }
#undef LOADB
#undef STEP

    #pragma unroll
    for (int rb = 0; rb < 2; ++rb) {
        #pragma unroll
        for (int r = 0; r < 4; ++r) {
            const int row = n0 + rb * 16 + kg * 4 + r;
            #pragma unroll
            for (int cb = 0; cb < 4; ++cb) {
                float4 vv = {acc[rb][cb][r], 0.f, 0.f, 0.f};
                __builtin_nontemporal_store(acc[rb][cb][r],
                    &pacc[((size_t)(s * NN + row)) * NC + h * 64 + cb * 16 + lr]);
            }
            if (lr == 0)
                pden[(s * NN + row) * 4 + h] = dacc[rb][r];
        }
    }
}

// ---------------------------------------------------------------------------
// Kernel 3: reduce splits, normalize, ReLU.
// ---------------------------------------------------------------------------
__global__ __launch_bounds__(256) void finalize_kernel(
    const float* __restrict__ pacc, const float* __restrict__ pden,
    float* __restrict__ out, int nsplit)
{
    const int n = blockIdx.x;
    const int c = threadIdx.x;
    float a = 0.f, d = 0.f;
    for (int s = 0; s < nsplit; ++s) {
        a += pacc[((size_t)(s * NN + n)) * NC + c];
        d += pden[(s * NN + n) * 4 + (c >> 6)];
    }
    const float o = (d > 0.f) ? a / d : 0.f;
    out[(size_t)n * NC + c] = o > 0.f ? o : 0.f;
}

// ---------------------------------------------------------------------------
extern "C" void kernel_launch(void* const* d_in, const int* in_sizes, int n_in,
                              void* d_out, int out_size, void* d_ws, size_t ws_size,
                              hipStream_t stream)
{
    const int*   adj   = (const int*)d_in[0];
    const float* feats = (const float*)d_in[1];
    const float* W     = (const float*)d_in[2];
    const float* ak    = (const float*)d_in[3];
    float*       out   = (float*)d_out;

    char* ws = (char*)d_ws;
    unsigned int* adjw  = (unsigned int*)ws;                          // 2 MB
    _Float16*     Bpack = (_Float16*)(ws + (2ull << 20));             // 2 MB
    _Float16*     Es    = (_Float16*)(ws + (4ull << 20));             // 32 KB
    _Float16*     Fs    = (_Float16*)(ws + (4ull << 20) + (1 << 16)); // 32 KB
    _Float16*     En    = (_Float16*)(ws + (4ull << 20) + (2 << 16)); // 32 KB
    _Float16*     Fn    = (_Float16*)(ws + (4ull << 20) + (3 << 16)); // 32 KB
    float*        pden  = (float*)(ws + (4ull << 20) + (4 << 16));    // <=512 KB
    float*        pacc  = (float*)(ws + (5ull << 20));                // nsplit*4 MB

    int nsplit = 8;
    while (nsplit > 1 && ws_size < (5ull << 20) + (size_t)nsplit * (4ull << 20))
        nsplit >>= 1;
    const int ksplit = NN / nsplit;

    adjbits_kernel<<<NN, 256, 0, stream>>>(adj, adjw);
    prep_kernel<<<dim3(128, 4), 256, 0, stream>>>(feats, W, ak, Bpack, Es, Fs, En, Fn);
    attn_kernel<<<dim3(128, 4, nsplit), 64, 0, stream>>>(adjw, Bpack, Es, Fs, En, Fn, pacc, pden, ksplit);
    finalize_kernel<<<NN, 256, 0, stream>>>(pacc, pden, out, nsplit);
}